// Round 5
// baseline (98.510 us; speedup 1.0000x reference)
//
#include <hip/hip_runtime.h>
#include <math.h>

#define BB 4
#define SS 4096
#define DD 768
#define HH 64
#define MM (BB * SS)

typedef __attribute__((ext_vector_type(8))) short bf16x8;
typedef __attribute__((ext_vector_type(4))) float f32x4;

__device__ inline unsigned short f2bf(float f) {
    union { float f; unsigned u; } x; x.f = f;
    unsigned r = x.u + 0x7fffu + ((x.u >> 16) & 1u);
    return (unsigned short)(r >> 16);
}

// ---------------- One-time weight transpose: Wq|Wk|Wv [768,64] fp32 -> Wt [192][768] bf16 ----------------
__global__ __launch_bounds__(256) void wt_kernel(
    const float* __restrict__ Wq, const float* __restrict__ Wk, const float* __restrict__ Wv,
    unsigned short* __restrict__ Wt)
{
    const int kt = blockIdx.x;
    const int sel = blockIdx.y;
    const int k0 = kt * 64;
    const float* W = (sel == 0) ? Wq : (sel == 1) ? Wk : Wv;
    __shared__ float Ws[64][68];
    const int t = threadIdx.x;
    #pragma unroll
    for (int j = 0; j < 4; ++j) {
        const int fl = t + j * 256;
        const int row = fl >> 4, c4 = (fl & 15) * 4;
        float4 v = *reinterpret_cast<const float4*>(&W[(size_t)(k0 + row) * HH + c4]);
        Ws[row][c4 + 0] = v.x; Ws[row][c4 + 1] = v.y;
        Ws[row][c4 + 2] = v.z; Ws[row][c4 + 3] = v.w;
    }
    __syncthreads();
    const int n = t >> 2;
    const int c8 = (t & 3) * 16;
    unsigned short tmp[16];
    #pragma unroll
    for (int j = 0; j < 16; ++j) tmp[j] = f2bf(Ws[c8 + j][n]);
    unsigned short* dst = &Wt[((size_t)sel * 64 + n) * DD + k0 + c8];
    *reinterpret_cast<bf16x8*>(dst)     = *reinterpret_cast<bf16x8*>(&tmp[0]);
    *reinterpret_cast<bf16x8*>(dst + 8) = *reinterpret_cast<bf16x8*>(&tmp[8]);
}

// ---------------- QKV projection via MFMA: M=64 tile, N=192, BK=64 ----------------
// 256 blocks x 512 threads. Waves: ms = w&3 (16-row strip), nq = w>>2 (96-col half).
#define PP 72
__global__ __launch_bounds__(512) void qkv_proj_kernel(
    const float* __restrict__ X, const unsigned short* __restrict__ Wt,
    const float* __restrict__ bq, const float* __restrict__ bk, const float* __restrict__ bv,
    unsigned short* __restrict__ Qb, unsigned short* __restrict__ Kb,
    unsigned short* __restrict__ Vt)
{
    __shared__ unsigned short Alds[64][PP];
    __shared__ unsigned short Blds[192][PP];

    const int tid = threadIdx.x;
    const int rowBase = blockIdx.x * 64;
    const int w = tid >> 6;
    const int ms = w & 3;
    const int nq = w >> 2;
    const int lane = tid & 63;
    const int lhi = lane >> 4, llo = lane & 15;

    f32x4 acc[6] = {{0,0,0,0},{0,0,0,0},{0,0,0,0},{0,0,0,0},{0,0,0,0},{0,0,0,0}};

    const int arow = tid >> 3;
    const int ac = (tid & 7) * 8;

    for (int kb = 0; kb < DD / 64; ++kb) {
        const int kBase = kb * 64;
        __syncthreads();
        // stage A: 64x64 fp32 -> bf16 (8 floats = 2 float4 per thread)
        {
            float4 v0 = *reinterpret_cast<const float4*>(
                &X[(size_t)(rowBase + arow) * DD + kBase + ac]);
            float4 v1 = *reinterpret_cast<const float4*>(
                &X[(size_t)(rowBase + arow) * DD + kBase + ac + 4]);
            unsigned short pk[8];
            pk[0] = f2bf(v0.x); pk[1] = f2bf(v0.y); pk[2] = f2bf(v0.z); pk[3] = f2bf(v0.w);
            pk[4] = f2bf(v1.x); pk[5] = f2bf(v1.y); pk[6] = f2bf(v1.z); pk[7] = f2bf(v1.w);
            *reinterpret_cast<bf16x8*>(&Alds[arow][ac]) = *reinterpret_cast<bf16x8*>(pk);
        }
        // stage B: 192x64 bf16 (3 bf16x8/thread)
        #pragma unroll
        for (int i = 0; i < 3; ++i) {
            const int u = tid + i * 512;
            const int n = u >> 3, c8 = (u & 7) * 8;
            *reinterpret_cast<bf16x8*>(&Blds[n][c8]) =
                *reinterpret_cast<const bf16x8*>(&Wt[(size_t)n * DD + kBase + c8]);
        }
        __syncthreads();

        #pragma unroll
        for (int kk = 0; kk < 2; ++kk) {
            const int aoff = kk * 32 + lhi * 8;
            bf16x8 af = *reinterpret_cast<const bf16x8*>(&Alds[ms * 16 + llo][aoff]);
            #pragma unroll
            for (int nt = 0; nt < 6; ++nt) {
                bf16x8 bf = *reinterpret_cast<const bf16x8*>(&Blds[nq * 96 + nt * 16 + llo][aoff]);
                acc[nt] = __builtin_amdgcn_mfma_f32_16x16x32_bf16(af, bf, acc[nt], 0, 0, 0);
            }
        }
    }

    #pragma unroll
    for (int nt = 0; nt < 6; ++nt) {
        const int n = nq * 96 + nt * 16 + llo;
        const int sel = n >> 6;
        const int nn = n & 63;
        const float bias = (sel == 0) ? bq[nn] : (sel == 1) ? bk[nn] : bv[nn];
        #pragma unroll
        for (int r = 0; r < 4; ++r) {
            const int row = rowBase + ms * 16 + lhi * 4 + r;
            const float val = acc[nt][r] + bias;
            if (sel == 0) {
                Qb[(size_t)row * HH + nn] = f2bf(val * 0.125f);
            } else if (sel == 1) {
                Kb[(size_t)row * HH + nn] = f2bf(val);
            } else {
                const int bb = row >> 12;
                const int s = row & (SS - 1);
                Vt[((size_t)bb * HH + nn) * SS + s] = f2bf(val);
            }
        }
    }
}

// ---------------- Split-K MFMA flash attention with async reg-prefetch staging ----------------
#define KP 72

union SMemA {
    struct { unsigned short K[2][64][KP]; unsigned short V[2][64][KP]; } st; // 36864 B
    struct { float O[64][68]; float ml[64][2]; } cb;                          // 17920 B
};

// Block = one (q-tile, key-chunk). Chunk = 16 KV tiles, 8 steps x 2 groups.
// 512 threads = 8 waves: g = w>>2 (KV-tile parity), wq = w&3 (16-row q strip).
__global__ __launch_bounds__(512, 4) void attn_partial_kernel(
    const unsigned short* __restrict__ Qg, const unsigned short* __restrict__ Kg,
    const unsigned short* __restrict__ Vtg, float* __restrict__ out,
    float* __restrict__ Po, float* __restrict__ Pml)
{
    __shared__ SMemA sm;
    __shared__ unsigned short Pl[8][16][KP];

    // decode (qb, c) from linear block id
    const int l = blockIdx.x;           // 0..159
    int gg, start;
    if (l < 16)      { gg = 0; start = 0; }
    else if (l < 48) { gg = 1; start = 16; }
    else if (l < 96) { gg = 2; start = 48; }
    else             { gg = 3; start = 96; }
    const int r_ = l - start;
    const int qb = 16 * gg + r_ / (gg + 1);
    const int c  = r_ % (gg + 1);

    const int tid = threadIdx.x;
    const int b  = blockIdx.y;
    const int q0 = qb * 64;
    const int w   = tid >> 6;        // 0..7
    const int g   = w >> 2;          // 0..1
    const int wq  = w & 3;
    const int lane = tid & 63;
    const int lhi = lane >> 4, llo = lane & 15;
    const int qw0 = q0 + wq * 16;

    const int ntiles = qb + 1;
    const int base0 = c * 16;
    const int endT = min(base0 + 16, ntiles);
    const int nsteps = (endT - base0 + 1) >> 1;
    const int nch = qb / 16 + 1;

    const unsigned short* Kbase = Kg  + (size_t)b * SS * HH;
    const unsigned short* Vbase = Vtg + (size_t)b * HH * SS;

    bf16x8 qf0, qf1;
    {
        const unsigned short* qrow = Qg + ((size_t)b * SS + qw0 + llo) * HH + lhi * 8;
        qf0 = *reinterpret_cast<const bf16x8*>(qrow);
        qf1 = *reinterpret_cast<const bf16x8*>(qrow + 32);
    }

    float m[4] = {-INFINITY, -INFINITY, -INFINITY, -INFINITY};
    float lsum[4] = {0.f, 0.f, 0.f, 0.f};
    f32x4 acc_o[4] = {{0,0,0,0},{0,0,0,0},{0,0,0,0},{0,0,0,0}};

    // staging coords: thread stages one bf16x8 per tile (2 K + 2 V)
    const int srow = tid >> 3;        // 0..63
    const int sc8  = (tid & 7) * 8;   // 0..56

    bf16x8 rA[4] = {{0,0,0,0,0,0,0,0},{0,0,0,0,0,0,0,0},{0,0,0,0,0,0,0,0},{0,0,0,0,0,0,0,0}};
    bf16x8 rB[4] = {{0,0,0,0,0,0,0,0},{0,0,0,0,0,0,0,0},{0,0,0,0,0,0,0,0},{0,0,0,0,0,0,0,0}};

    auto load_step = [&](int base, bf16x8 (&rg)[4]) {
        #pragma unroll
        for (int i = 0; i < 4; ++i) {
            const int t = base + (i & 1);
            if (t < endT) {
                rg[i] = (i < 2)
                    ? *reinterpret_cast<const bf16x8*>(&Kbase[(size_t)(t * 64 + srow) * HH + sc8])
                    : *reinterpret_cast<const bf16x8*>(&Vbase[(size_t)srow * SS + t * 64 + sc8]);
            }
        }
    };
    auto write_step = [&](bf16x8 (&rg)[4]) {
        *reinterpret_cast<bf16x8*>(&sm.st.K[0][srow][sc8]) = rg[0];
        *reinterpret_cast<bf16x8*>(&sm.st.K[1][srow][sc8]) = rg[1];
        *reinterpret_cast<bf16x8*>(&sm.st.V[0][srow][sc8]) = rg[2];
        *reinterpret_cast<bf16x8*>(&sm.st.V[1][srow][sc8]) = rg[3];
    };

    load_step(base0, rA);

    for (int stp = 0; stp < nsteps; ++stp) {
        const int base = base0 + stp * 2;
        __syncthreads();   // previous step's LDS readers done
        if ((stp & 1) == 0) {
            write_step(rA);
            if (stp + 1 < nsteps) load_step(base + 2, rB);   // in flight during compute
        } else {
            write_step(rB);
            if (stp + 1 < nsteps) load_step(base + 2, rA);
        }
        __syncthreads();   // LDS ready

        const int lt = base + g;
        if (lt < endT) {
            const int k0 = lt * 64;
            const unsigned short (&Ks)[64][KP] = sm.st.K[g];
            const unsigned short (&Vs)[64][KP] = sm.st.V[g];

            // ---- S = Q K^T ----
            f32x4 sacc[4] = {{0,0,0,0},{0,0,0,0},{0,0,0,0},{0,0,0,0}};
            #pragma unroll
            for (int kt = 0; kt < 4; ++kt) {
                bf16x8 kfa = *reinterpret_cast<const bf16x8*>(&Ks[kt * 16 + llo][lhi * 8]);
                bf16x8 kfb = *reinterpret_cast<const bf16x8*>(&Ks[kt * 16 + llo][32 + lhi * 8]);
                sacc[kt] = __builtin_amdgcn_mfma_f32_16x16x32_bf16(qf0, kfa, sacc[kt], 0, 0, 0);
                sacc[kt] = __builtin_amdgcn_mfma_f32_16x16x32_bf16(qf1, kfb, sacc[kt], 0, 0, 0);
            }

            // ---- causal mask ----
            if (k0 + 63 > qw0) {
                #pragma unroll
                for (int kt = 0; kt < 4; ++kt) {
                    const int k = k0 + kt * 16 + llo;
                    #pragma unroll
                    for (int r = 0; r < 4; ++r) {
                        const int q = qw0 + lhi * 4 + r;
                        if (k > q) sacc[kt][r] = -INFINITY;
                    }
                }
            }

            // ---- online softmax ----
            float p[4][4];
            #pragma unroll
            for (int r = 0; r < 4; ++r) {
                float mx = fmaxf(fmaxf(sacc[0][r], sacc[1][r]), fmaxf(sacc[2][r], sacc[3][r]));
                mx = fmaxf(mx, __shfl_xor(mx, 1));
                mx = fmaxf(mx, __shfl_xor(mx, 2));
                mx = fmaxf(mx, __shfl_xor(mx, 4));
                mx = fmaxf(mx, __shfl_xor(mx, 8));
                const float mn = fmaxf(m[r], mx);
                const float corr = __expf(m[r] - mn);
                float ps = 0.f;
                #pragma unroll
                for (int kt = 0; kt < 4; ++kt) { p[kt][r] = __expf(sacc[kt][r] - mn); ps += p[kt][r]; }
                ps += __shfl_xor(ps, 1);
                ps += __shfl_xor(ps, 2);
                ps += __shfl_xor(ps, 4);
                ps += __shfl_xor(ps, 8);
                lsum[r] = lsum[r] * corr + ps;
                m[r] = mn;
                #pragma unroll
                for (int dt = 0; dt < 4; ++dt) acc_o[dt][r] *= corr;
            }

            // ---- P -> LDS (same-wave roundtrip) ----
            #pragma unroll
            for (int kt = 0; kt < 4; ++kt)
                #pragma unroll
                for (int r = 0; r < 4; ++r)
                    Pl[w][lhi * 4 + r][kt * 16 + llo] = f2bf(p[kt][r]);

            bf16x8 pf0 = *reinterpret_cast<const bf16x8*>(&Pl[w][llo][lhi * 8]);
            bf16x8 pf1 = *reinterpret_cast<const bf16x8*>(&Pl[w][llo][32 + lhi * 8]);

            // ---- O += P V ----
            #pragma unroll
            for (int dt = 0; dt < 4; ++dt) {
                bf16x8 vfa = *reinterpret_cast<const bf16x8*>(&Vs[dt * 16 + llo][lhi * 8]);
                bf16x8 vfb = *reinterpret_cast<const bf16x8*>(&Vs[dt * 16 + llo][32 + lhi * 8]);
                acc_o[dt] = __builtin_amdgcn_mfma_f32_16x16x32_bf16(pf0, vfa, acc_o[dt], 0, 0, 0);
                acc_o[dt] = __builtin_amdgcn_mfma_f32_16x16x32_bf16(pf1, vfb, acc_o[dt], 0, 0, 0);
            }
        }
    }

    // ---- 2-way in-block flash combine ----
    __syncthreads();
    if (g == 1) {
        #pragma unroll
        for (int dt = 0; dt < 4; ++dt)
            #pragma unroll
            for (int r = 0; r < 4; ++r)
                sm.cb.O[wq * 16 + lhi * 4 + r][dt * 16 + llo] = acc_o[dt][r];
        if (llo == 0) {
            #pragma unroll
            for (int r = 0; r < 4; ++r) {
                sm.cb.ml[wq * 16 + lhi * 4 + r][0] = m[r];
                sm.cb.ml[wq * 16 + lhi * 4 + r][1] = lsum[r];
            }
        }
    }
    __syncthreads();
    if (g == 0) {
        float* PoT  = Po  + (((size_t)(b * 64 + qb) * 4 + c) << 12);
        float* PmlT = Pml + (((size_t)(b * 64 + qb) * 4 + c) << 7);
        #pragma unroll
        for (int r = 0; r < 4; ++r) {
            const int row = wq * 16 + lhi * 4 + r;
            const float mg = sm.cb.ml[row][0];
            const float lg = sm.cb.ml[row][1];
            const float M = fmaxf(m[r], mg);
            const float a0 = __expf(m[r] - M);
            const float a1 = __expf(mg - M);
            const float L = lsum[r] * a0 + lg * a1;
            if (nch == 1) {
                const float invL = 1.f / L;
                const size_t orow = ((size_t)b * SS + q0 + row) * HH;
                #pragma unroll
                for (int dt = 0; dt < 4; ++dt) {
                    const float o = acc_o[dt][r] * a0 + sm.cb.O[row][dt * 16 + llo] * a1;
                    out[orow + dt * 16 + llo] = o * invL;
                }
            } else {
                #pragma unroll
                for (int dt = 0; dt < 4; ++dt) {
                    const float o = acc_o[dt][r] * a0 + sm.cb.O[row][dt * 16 + llo] * a1;
                    PoT[row * 64 + dt * 16 + llo] = o;
                }
                if (llo == 0) { PmlT[row] = M; PmlT[64 + row] = L; }
            }
        }
    }
}

// ---------------- Partial combine: q-tiles 16..63 (2..4 chunks each) ----------------
__global__ __launch_bounds__(256) void combine_kernel(
    const float* __restrict__ Po, const float* __restrict__ Pml, float* __restrict__ out)
{
    const int qt = 16 + blockIdx.x;
    const int b  = blockIdx.y;
    const int nch = qt / 16 + 1;
    const int t = threadIdx.x;
    const int row = t >> 2;
    const int col0 = (t & 3) * 16;
    const size_t baseIdx = (size_t)(b * 64 + qt) * 4;

    float mv[4], lv[4], a[4];
    float M = -INFINITY;
    for (int cc = 0; cc < nch; ++cc) {
        const float* PmlT = Pml + ((baseIdx + cc) << 7);
        mv[cc] = PmlT[row];
        lv[cc] = PmlT[64 + row];
        M = fmaxf(M, mv[cc]);
    }
    float L = 0.f;
    for (int cc = 0; cc < nch; ++cc) { a[cc] = __expf(mv[cc] - M); L += a[cc] * lv[cc]; }
    const float invL = 1.f / L;

    #pragma unroll
    for (int j = 0; j < 4; ++j) {
        float4 s = {0.f, 0.f, 0.f, 0.f};
        for (int cc = 0; cc < nch; ++cc) {
            const float4 v = *reinterpret_cast<const float4*>(
                &Po[((baseIdx + cc) << 12) + row * 64 + col0 + j * 4]);
            s.x += a[cc] * v.x; s.y += a[cc] * v.y;
            s.z += a[cc] * v.z; s.w += a[cc] * v.w;
        }
        s.x *= invL; s.y *= invL; s.z *= invL; s.w *= invL;
        *reinterpret_cast<float4*>(&out[((size_t)b * SS + qt * 64 + row) * HH + col0 + j * 4]) = s;
    }
}

extern "C" void kernel_launch(void* const* d_in, const int* in_sizes, int n_in,
                              void* d_out, int out_size, void* d_ws, size_t ws_size,
                              hipStream_t stream)
{
    const float* X  = (const float*)d_in[0];
    const float* Wq = (const float*)d_in[1];
    const float* bq = (const float*)d_in[2];
    const float* Wk = (const float*)d_in[3];
    const float* bk = (const float*)d_in[4];
    const float* Wv = (const float*)d_in[5];
    const float* bv = (const float*)d_in[6];

    unsigned short* Qb = (unsigned short*)d_ws;          // 2 MB
    unsigned short* Kb = Qb + (size_t)MM * HH;           // 2 MB
    unsigned short* Vt = Kb + (size_t)MM * HH;           // 2 MB (transposed [B][H][S])
    unsigned short* Wt = Vt + (size_t)MM * HH;           // 288 KB
    float* Po  = (float*)(Wt + (size_t)192 * DD);        // 16 MB
    float* Pml = Po + ((size_t)BB * 64 * 4 << 12);       // 512 KB

    dim3 gw(DD / 64, 3);
    wt_kernel<<<gw, 256, 0, stream>>>(Wq, Wk, Wv, Wt);

    qkv_proj_kernel<<<MM / 64, 512, 0, stream>>>(X, Wt, bq, bk, bv, Qb, Kb, Vt);

    dim3 ga(160, BB);
    attn_partial_kernel<<<ga, 512, 0, stream>>>(Qb, Kb, Vt, (float*)d_out, Po, Pml);
    dim3 gc(48, BB);
    combine_kernel<<<gc, 256, 0, stream>>>(Po, Pml, (float*)d_out);
}